// Round 2
// baseline (363.555 us; speedup 1.0000x reference)
//
#include <hip/hip_runtime.h>
#include <hip/hip_bf16.h>
#include <math.h>

#define BB 32
#define NN 128
#define HH 8
#define EE 64
#define CC 16
#define DD 512  // HH*EE

#define NEG_BIG (-1.0e30f)

// ---- bf16 helpers (raw-bit, bf16 -> f32 is a 16-bit shift) ----
__device__ __forceinline__ float bf2f(unsigned short u) {
    union { unsigned int i; float f; } x; x.i = ((unsigned int)u) << 16; return x.f;
}
__device__ __forceinline__ float bflo(unsigned int u) {
    union { unsigned int i; float f; } x; x.i = u << 16; return x.f;
}
__device__ __forceinline__ float bfhi(unsigned int u) {
    union { unsigned int i; float f; } x; x.i = u & 0xffff0000u; return x.f;
}
__device__ __forceinline__ unsigned short f2bf(float f) {
    union { float f; unsigned int i; } x; x.f = f;
    unsigned int r = x.i + 0x7fffu + ((x.i >> 16) & 1u);  // RNE
    return (unsigned short)(r >> 16);
}

template <bool F32>
__device__ __forceinline__ float ldx(const void* p, int i) {
    if constexpr (F32) return ((const float*)p)[i];
    else               return bf2f(((const unsigned short*)p)[i]);
}

// wave-local LDS fence: lds_w is wave-private, so no block barrier is needed.
// LDS ops retire in-order within a wave; the waitcnt + compiler barrier is enough.
__device__ __forceinline__ void wave_lds_sync() {
    asm volatile("s_waitcnt lgkmcnt(0)" ::: "memory");
    __builtin_amdgcn_wave_barrier();
}

// head configs replicated from auto_head_configs(8, 128) (verified by enumeration):
// K = {3,5,3,5,3,5,3,3}, d = {1,5,19,14,37,23,55,63}
__device__ const int g_dil[8] = {1, 5, 19, 14, 37, 23, 55, 63};

// ---------------- dtype detector: writes flag (1 = f32 inputs, 0 = bf16 inputs) ----
__global__ void detect_dtype(const unsigned short* __restrict__ q, int* __restrict__ flag) {
    const int lane = threadIdx.x;  // 64 threads
    int outliers = 0;
    #pragma unroll
    for (int i = 0; i < 16; ++i) {
        unsigned short u = q[(i * 64 + lane) * 2];
        int e = (u >> 7) & 0xFF;
        int sane = (e >= 101 && e <= 140) || ((u & 0x7FFFu) == 0);
        outliers += !sane;
    }
    #pragma unroll
    for (int m = 32; m >= 1; m >>= 1) outliers += __shfl_xor(outliers, m, 64);
    if (lane == 0) *flag = (outliers > 256) ? 1 : 0;
}

// ---------------- Kernel A: gate = sigmoid(gelu(mean_n(V) @ w1 + b1) @ w2 + b2) ----
// 1024 threads/block (16 waves): 512 blocks x 16 waves = 32 waves/CU (full occupancy)
// vs the old 256-thread version's 8 waves/CU (25%), which left the 134 MB pool read
// latency-bound at ~1.7 TB/s.
template <bool F32>
__global__ __launch_bounds__(1024) void gate_kernel(
    const void* __restrict__ values,  // [B,C,N,D]
    const void* __restrict__ w1,      // [D, D/4]
    const void* __restrict__ b1,      // [D/4]
    const void* __restrict__ w2,      // [D/4]
    const void* __restrict__ b2,      // [1]
    const int*  __restrict__ flag,
    float* __restrict__ gate_out)     // [B*C] f32
{
    if (*flag != (F32 ? 1 : 0)) return;
    __shared__ float vps[4][DD];      // per-group partial sums (8 KB)
    __shared__ float vp[DD];
    __shared__ float hidp[4][DD / 4];
    __shared__ float hid[DD / 4];
    const int bc  = blockIdx.x;       // b*C + c
    const int t   = threadIdx.x;      // 0..1023
    const int grp = t >> 8;           // 0..3: owns 32 of the 128 n-rows
    const int tt  = t & 255;          // owns 2 adjacent d-columns
    float a0 = 0.f, a1 = 0.f;
    if constexpr (F32) {
        const float2* vb = (const float2*)((const float*)values + (size_t)bc * NN * DD)
                           + (size_t)(grp * 32) * (DD / 2);
        #pragma unroll 8
        for (int n = 0; n < 32; ++n) { float2 u = vb[n * (DD / 2) + tt]; a0 += u.x; a1 += u.y; }
    } else {
        const unsigned int* vb = (const unsigned int*)((const unsigned short*)values + (size_t)bc * NN * DD)
                                 + (size_t)(grp * 32) * (DD / 2);
        #pragma unroll 8
        for (int n = 0; n < 32; ++n) { unsigned int u = vb[n * (DD / 2) + tt]; a0 += bflo(u); a1 += bfhi(u); }
    }
    vps[grp][2 * tt]     = a0;
    vps[grp][2 * tt + 1] = a1;
    __syncthreads();
    if (t < 256) {
        float s0 = vps[0][2 * t]     + vps[1][2 * t]     + vps[2][2 * t]     + vps[3][2 * t];
        float s1 = vps[0][2 * t + 1] + vps[1][2 * t + 1] + vps[2][2 * t + 1] + vps[3][2 * t + 1];
        vp[2 * t]     = s0 * (1.0f / NN);
        vp[2 * t + 1] = s1 * (1.0f / NN);
    }
    __syncthreads();
    if (t < 512) {                    // 4-way split of the D-dim dot per hidden unit
        const int o  = t & 127;
        const int ch = t >> 7;
        float a = 0.f;
        #pragma unroll 4
        for (int dd = ch * 128; dd < ch * 128 + 128; ++dd)
            a += vp[dd] * ldx<F32>(w1, dd * (DD / 4) + o);
        hidp[ch][o] = a;
    }
    __syncthreads();
    if (t < 128) {
        float a = ldx<F32>(b1, t) + hidp[0][t] + hidp[1][t] + hidp[2][t] + hidp[3][t];
        hid[t] = 0.5f * a * (1.0f + erff(a * 0.70710678118654752440f));  // exact gelu
    }
    __syncthreads();
    if (t < 64) {
        float s = hid[t] * ldx<F32>(w2, t) + hid[t + 64] * ldx<F32>(w2, t + 64);
        #pragma unroll
        for (int m = 32; m >= 1; m >>= 1) s += __shfl_xor(s, m, 64);
        if (t == 0) {
            float z = s + ldx<F32>(b2, 0);
            gate_out[bc] = 1.0f / (1.0f + expf(-z));
        }
    }
}

// ---------------- Kernel B: sparse neighborhood attention, 1 wave per (b,h,n) ----
// Score phase: 4 lanes per (c,k) pair (g = lane>>2 -> exo-var c, sub = lane&3 -> 16-dim
// E slice), wave-uniform j. Branchless: invalid j clamped to the (always-valid, L1-hot)
// self row n; its softmax weight is exactly 0 so the V-phase contribution vanishes.
// V phase: lane = (c-parity, channel-pair) -> float2 loads covering 2 channels x 2
// exo-vars per instruction (half the instruction count), shfl_xor(32) combine.
// No __syncthreads: lds_w is wave-private.
template <bool F32>
__global__ __launch_bounds__(256) void attn_kernel(
    const void* __restrict__ qptr,  // [B,N,H,E]
    const void* __restrict__ kptr,  // [B,C,N,H,E]
    const void* __restrict__ vptr,  // [B,C,N,H,E]
    const float* __restrict__ gate, // [B*C]
    const int*  __restrict__ flag,
    void* __restrict__ optr)        // [B,N,H,E]
{
    if (*flag != (F32 ? 1 : 0)) return;
    __shared__ float lds_w[4][CC * 5];   // raw scores, then normalized gated weights
    const int tid  = threadIdx.x;
    const int wave = tid >> 6;
    const int lane = tid & 63;

    // XCD-locality swizzle: phys block p -> XCD p%8 (round-robin assumption).
    // virt = ((p&7)<<10)|(p>>3) gives each XCD a contiguous range of (b,h) groups
    // so the ~1MB per-(b,h) key/value working set stays L2-resident.
    const int p    = blockIdx.x;
    const int virt = ((p & 7) << 10) | (p >> 3);
    const int gw   = virt * 4 + wave;       // (b*H + h)*N + n
    const int n = gw & (NN - 1);
    const int h = (gw >> 7) & (HH - 1);
    const int b = gw >> 10;
    const int K   = ((h & 1) && (h != 7)) ? 5 : 3;
    const int dil = g_dil[h];
    const int nb  = CC * K;                 // 48 or 80 candidate pairs

    const int g   = lane >> 2;              // exo-var c owned by this 4-lane group
    const int sub = lane & 3;               // 16-dim slice of E

    const size_t qoff  = (((size_t)b * NN + n) * HH + h) * EE;
    const size_t kvoff = ((size_t)b * CC * NN) * DD + (size_t)h * EE;

    // q slice (16 dims) into registers, scale folded in
    float qreg[16];
    if constexpr (F32) {
        const float4* qp = (const float4*)((const float*)qptr + qoff + sub * 16);
        #pragma unroll
        for (int i = 0; i < 4; ++i) {
            float4 u = qp[i];
            qreg[4 * i + 0] = u.x * 0.125f; qreg[4 * i + 1] = u.y * 0.125f;
            qreg[4 * i + 2] = u.z * 0.125f; qreg[4 * i + 3] = u.w * 0.125f;
        }
    } else {
        const uint4* qp = (const uint4*)((const unsigned short*)qptr + qoff + sub * 16);
        #pragma unroll
        for (int i = 0; i < 2; ++i) {
            uint4 u = qp[i];
            qreg[8 * i + 0] = bflo(u.x) * 0.125f; qreg[8 * i + 1] = bfhi(u.x) * 0.125f;
            qreg[8 * i + 2] = bflo(u.y) * 0.125f; qreg[8 * i + 3] = bfhi(u.y) * 0.125f;
            qreg[8 * i + 4] = bflo(u.z) * 0.125f; qreg[8 * i + 5] = bfhi(u.z) * 0.125f;
            qreg[8 * i + 6] = bflo(u.w) * 0.125f; qreg[8 * i + 7] = bfhi(u.w) * 0.125f;
        }
    }

    // ---- scores: pass k covers all 16 exo vars, branchless (clamped j) ----
    const size_t rowbase = kvoff + (size_t)g * NN * DD + (size_t)sub * 16;
    #pragma unroll 5
    for (int k = 0; k < K; ++k) {
        int jr = n + (k - (K >> 1)) * dil;
        bool valid = (jr >= 0) && (jr < NN);
        int j = valid ? jr : n;              // self row: L1-hot, weight will be 0
        size_t off = rowbase + (size_t)j * DD;
        float a0 = 0.f, a1 = 0.f, a2 = 0.f, a3 = 0.f;
        if constexpr (F32) {
            const float4* kp = (const float4*)((const float*)kptr + off);
            #pragma unroll
            for (int i = 0; i < 4; ++i) {
                float4 kk = kp[i];
                a0 += qreg[4 * i + 0] * kk.x; a1 += qreg[4 * i + 1] * kk.y;
                a2 += qreg[4 * i + 2] * kk.z; a3 += qreg[4 * i + 3] * kk.w;
            }
        } else {
            const uint4* kp = (const uint4*)((const unsigned short*)kptr + off);
            #pragma unroll
            for (int i = 0; i < 2; ++i) {
                uint4 kk = kp[i];
                a0 += qreg[8 * i + 0] * bflo(kk.x); a1 += qreg[8 * i + 1] * bfhi(kk.x);
                a2 += qreg[8 * i + 2] * bflo(kk.y); a3 += qreg[8 * i + 3] * bfhi(kk.y);
                a0 += qreg[8 * i + 4] * bflo(kk.z); a1 += qreg[8 * i + 5] * bfhi(kk.z);
                a2 += qreg[8 * i + 6] * bflo(kk.w); a3 += qreg[8 * i + 7] * bfhi(kk.w);
            }
        }
        float s = (a0 + a1) + (a2 + a3);
        s += __shfl_xor(s, 1, 64);           // 4-lane butterfly -> full dot in all 4 lanes
        s += __shfl_xor(s, 2, 64);
        s = valid ? s : NEG_BIG;
        if (sub == 0) lds_w[wave][k * CC + g] = s;
    }
    wave_lds_sync();

    // ---- softmax over the wave's pairs (self pair j==n always valid) ----
    float s0 = (lane < nb) ? lds_w[wave][lane] : NEG_BIG;
    float s1 = (nb > 64 && lane + 64 < nb) ? lds_w[wave][lane + 64] : NEG_BIG;
    float m = fmaxf(s0, s1);
    #pragma unroll
    for (int mm = 32; mm >= 1; mm >>= 1) m = fmaxf(m, __shfl_xor(m, mm, 64));
    float e0 = (s0 <= NEG_BIG) ? 0.f : expf(s0 - m);
    float e1 = (s1 <= NEG_BIG) ? 0.f : expf(s1 - m);
    float tsum = e0 + e1;
    #pragma unroll
    for (int mm = 32; mm >= 1; mm >>= 1) tsum += __shfl_xor(tsum, mm, 64);
    float inv = 1.0f / tsum;
    float gv  = gate[b * CC + (lane & 15)];  // 2KB array, L2-hot broadcast
    lds_w[wave][lane] = e0 * inv * gv;       // gate folded into weight
    if (nb > 64 && lane + 64 < nb)
        lds_w[wave][lane + 64] = e1 * inv * gv;
    wave_lds_sync();

    // ---- output: channel-pair per lane, 2 exo-vars per instruction, branchless ----
    const int e2   = lane & 31;              // channels 2*e2, 2*e2+1
    const int cpar = lane >> 5;              // c parity handled by this half-wave
    float acc0 = 0.f, acc1 = 0.f;
    #pragma unroll 5
    for (int k = 0; k < K; ++k) {
        int jr = n + (k - (K >> 1)) * dil;
        int j = (jr >= 0 && jr < NN) ? jr : n;   // weight is 0 for invalid -> no-op
        const float* wrow = lds_w[wave] + k * CC;
        const size_t rbase = kvoff + (size_t)j * DD + 2 * e2;
        #pragma unroll
        for (int cc2 = 0; cc2 < CC / 2; ++cc2) {
            int c = 2 * cc2 + cpar;
            float w = wrow[c];
            size_t o = rbase + (size_t)c * (NN * DD);
            if constexpr (F32) {
                const float2 v = *(const float2*)((const float*)vptr + o);
                acc0 += w * v.x; acc1 += w * v.y;
            } else {
                unsigned int v = *(const unsigned int*)((const unsigned short*)vptr + o);
                acc0 += w * bflo(v); acc1 += w * bfhi(v);
            }
        }
    }
    acc0 += __shfl_xor(acc0, 32, 64);
    acc1 += __shfl_xor(acc1, 32, 64);
    if (lane < 32) {
        if constexpr (F32) {
            float2 r; r.x = acc0; r.y = acc1;
            ((float2*)((float*)optr + qoff))[e2] = r;
        } else {
            unsigned int pk = ((unsigned int)f2bf(acc1) << 16) | (unsigned int)f2bf(acc0);
            ((unsigned int*)((unsigned short*)optr + qoff))[e2] = pk;
        }
    }
}

extern "C" void kernel_launch(void* const* d_in, const int* in_sizes, int n_in,
                              void* d_out, int out_size, void* d_ws, size_t ws_size,
                              hipStream_t stream) {
    const void* queries = d_in[0];
    const void* keys    = d_in[1];
    const void* values  = d_in[2];
    const void* w1      = d_in[3];
    const void* b1      = d_in[4];
    const void* w2      = d_in[5];
    const void* b2      = d_in[6];
    // d_in[7] = na_mask: unused — neighborhood structure is regenerated analytically

    int*   flag    = (int*)d_ws;                    // 1 int
    float* gate_ws = (float*)d_ws + 64;             // B*C floats, offset 256 B

    hipLaunchKernelGGL(detect_dtype, dim3(1), dim3(64), 0, stream,
                       (const unsigned short*)queries, flag);
    hipLaunchKernelGGL((gate_kernel<false>), dim3(BB * CC), dim3(1024), 0, stream,
                       values, w1, b1, w2, b2, flag, gate_ws);
    hipLaunchKernelGGL((gate_kernel<true>), dim3(BB * CC), dim3(1024), 0, stream,
                       values, w1, b1, w2, b2, flag, gate_ws);
    hipLaunchKernelGGL((attn_kernel<false>), dim3(BB * HH * NN / 4), dim3(256), 0, stream,
                       queries, keys, values, gate_ws, flag, d_out);
    hipLaunchKernelGGL((attn_kernel<true>), dim3(BB * HH * NN / 4), dim3(256), 0, stream,
                       queries, keys, values, gate_ws, flag, d_out);
}

// Round 3
// 339.020 us; speedup vs baseline: 1.0724x; 1.0724x over previous
//
#include <hip/hip_runtime.h>
#include <hip/hip_bf16.h>
#include <math.h>

#define BB 32
#define NN 128
#define HH 8
#define EE 64
#define CC 16
#define DD 512  // HH*EE

#define NEG_BIG (-1.0e30f)

// ---- bf16 helpers (raw-bit, bf16 -> f32 is a 16-bit shift) ----
__device__ __forceinline__ float bf2f(unsigned short u) {
    union { unsigned int i; float f; } x; x.i = ((unsigned int)u) << 16; return x.f;
}
__device__ __forceinline__ float bflo(unsigned int u) {
    union { unsigned int i; float f; } x; x.i = u << 16; return x.f;
}
__device__ __forceinline__ float bfhi(unsigned int u) {
    union { unsigned int i; float f; } x; x.i = u & 0xffff0000u; return x.f;
}
__device__ __forceinline__ unsigned short f2bf(float f) {
    union { float f; unsigned int i; } x; x.f = f;
    unsigned int r = x.i + 0x7fffu + ((x.i >> 16) & 1u);  // RNE
    return (unsigned short)(r >> 16);
}

template <bool F32>
__device__ __forceinline__ float ldx(const void* p, int i) {
    if constexpr (F32) return ((const float*)p)[i];
    else               return bf2f(((const unsigned short*)p)[i]);
}

// head configs replicated from auto_head_configs(8, 128) (verified by enumeration):
// K = {3,5,3,5,3,5,3,3}, d = {1,5,19,14,37,23,55,63}
// dil packed as bytes of a u64 so the lookup is pure SALU (no memory load).
#define DIL_PACK 0x3F3717250E130501ull

// ---------------- dtype detector: writes flag (1 = f32 inputs, 0 = bf16 inputs) ----
__global__ void detect_dtype(const unsigned short* __restrict__ q, int* __restrict__ flag) {
    const int lane = threadIdx.x;  // 64 threads
    int outliers = 0;
    #pragma unroll
    for (int i = 0; i < 16; ++i) {
        unsigned short u = q[(i * 64 + lane) * 2];
        int e = (u >> 7) & 0xFF;
        int sane = (e >= 101 && e <= 140) || ((u & 0x7FFFu) == 0);
        outliers += !sane;
    }
    #pragma unroll
    for (int m = 32; m >= 1; m >>= 1) outliers += __shfl_xor(outliers, m, 64);
    if (lane == 0) *flag = (outliers > 256) ? 1 : 0;
}

// ---------------- Kernel A: gate = sigmoid(gelu(mean_n(V) @ w1 + b1) @ w2 + b2) ----
// 1024 threads/block (16 waves), dtype branch inside (block-uniform flag read).
template <bool F32>
__device__ __forceinline__ void gate_body(
    const void* __restrict__ values, const void* __restrict__ w1,
    const void* __restrict__ b1, const void* __restrict__ w2,
    const void* __restrict__ b2, float* __restrict__ gate_out,
    float (&vps)[4][DD], float (&vp)[DD], float (&hidp)[4][DD / 4], float (&hid)[DD / 4])
{
    const int bc  = blockIdx.x;       // b*C + c
    const int t   = threadIdx.x;      // 0..1023
    const int grp = t >> 8;           // 0..3: owns 32 of the 128 n-rows
    const int tt  = t & 255;          // owns 2 adjacent d-columns
    float a0 = 0.f, a1 = 0.f;
    if constexpr (F32) {
        const float2* vb = (const float2*)((const float*)values + (size_t)bc * NN * DD)
                           + (size_t)(grp * 32) * (DD / 2);
        #pragma unroll 8
        for (int n = 0; n < 32; ++n) { float2 u = vb[n * (DD / 2) + tt]; a0 += u.x; a1 += u.y; }
    } else {
        const unsigned int* vb = (const unsigned int*)((const unsigned short*)values + (size_t)bc * NN * DD)
                                 + (size_t)(grp * 32) * (DD / 2);
        #pragma unroll 8
        for (int n = 0; n < 32; ++n) { unsigned int u = vb[n * (DD / 2) + tt]; a0 += bflo(u); a1 += bfhi(u); }
    }
    vps[grp][2 * tt]     = a0;
    vps[grp][2 * tt + 1] = a1;
    __syncthreads();
    if (t < 256) {
        float s0 = vps[0][2 * t]     + vps[1][2 * t]     + vps[2][2 * t]     + vps[3][2 * t];
        float s1 = vps[0][2 * t + 1] + vps[1][2 * t + 1] + vps[2][2 * t + 1] + vps[3][2 * t + 1];
        vp[2 * t]     = s0 * (1.0f / NN);
        vp[2 * t + 1] = s1 * (1.0f / NN);
    }
    __syncthreads();
    if (t < 512) {                    // 4-way split of the D-dim dot per hidden unit
        const int o  = t & 127;
        const int ch = t >> 7;
        float a = 0.f;
        #pragma unroll 4
        for (int dd = ch * 128; dd < ch * 128 + 128; ++dd)
            a += vp[dd] * ldx<F32>(w1, dd * (DD / 4) + o);
        hidp[ch][o] = a;
    }
    __syncthreads();
    if (t < 128) {
        float a = ldx<F32>(b1, t) + hidp[0][t] + hidp[1][t] + hidp[2][t] + hidp[3][t];
        hid[t] = 0.5f * a * (1.0f + erff(a * 0.70710678118654752440f));  // exact gelu
    }
    __syncthreads();
    if (t < 64) {
        float s = hid[t] * ldx<F32>(w2, t) + hid[t + 64] * ldx<F32>(w2, t + 64);
        #pragma unroll
        for (int m = 32; m >= 1; m >>= 1) s += __shfl_xor(s, m, 64);
        if (t == 0) {
            float z = s + ldx<F32>(b2, 0);
            gate_out[bc] = 1.0f / (1.0f + expf(-z));
        }
    }
}

__global__ __launch_bounds__(1024) void gate_kernel(
    const void* __restrict__ values, const void* __restrict__ w1,
    const void* __restrict__ b1, const void* __restrict__ w2,
    const void* __restrict__ b2, const int* __restrict__ flag,
    float* __restrict__ gate_out)
{
    __shared__ float vps[4][DD];
    __shared__ float vp[DD];
    __shared__ float hidp[4][DD / 4];
    __shared__ float hid[DD / 4];
    if (*flag) gate_body<true >(values, w1, b1, w2, b2, gate_out, vps, vp, hidp, hid);
    else       gate_body<false>(values, w1, b1, w2, b2, gate_out, vps, vp, hidp, hid);
}

// ---------------- Kernel B: sparse neighborhood attention, 1 wave per (b,h,n) ----
// R1-proven structure (87 us): 4 lanes per (c,k) score pair, wave-uniform j skip
// branches (NO clamping - R2 showed clamped loads cost +13% FETCH and +18 us),
// scalar lane=channel V loads. New vs R1: compile-time K (h is block-uniform),
// V loads batched 16-wide per tap (one waitcnt per tap instead of four).
template <bool F32, int K>
__device__ __forceinline__ void attn_body(
    const void* __restrict__ qptr, const void* __restrict__ kptr,
    const void* __restrict__ vptr, const float* __restrict__ gate,
    void* __restrict__ optr,
    int b, int h, int n, int dil, int wave, int lane,
    float (&lds_w)[4][CC * 5])
{
    constexpr int nb = CC * K;              // 48 or 80 candidate pairs
    const int g   = lane >> 2;              // exo-var c owned by this 4-lane group
    const int sub = lane & 3;               // 16-dim slice of E

    const size_t qoff  = (((size_t)b * NN + n) * HH + h) * EE;
    const size_t kvoff = ((size_t)b * CC * NN) * DD + (size_t)h * EE;

    // q slice (16 dims) into registers, scale folded in
    float qreg[16];
    if constexpr (F32) {
        const float4* qp = (const float4*)((const float*)qptr + qoff + sub * 16);
        #pragma unroll
        for (int i = 0; i < 4; ++i) {
            float4 u = qp[i];
            qreg[4 * i + 0] = u.x * 0.125f; qreg[4 * i + 1] = u.y * 0.125f;
            qreg[4 * i + 2] = u.z * 0.125f; qreg[4 * i + 3] = u.w * 0.125f;
        }
    } else {
        const uint4* qp = (const uint4*)((const unsigned short*)qptr + qoff + sub * 16);
        #pragma unroll
        for (int i = 0; i < 2; ++i) {
            uint4 u = qp[i];
            qreg[8 * i + 0] = bflo(u.x) * 0.125f; qreg[8 * i + 1] = bfhi(u.x) * 0.125f;
            qreg[8 * i + 2] = bflo(u.y) * 0.125f; qreg[8 * i + 3] = bfhi(u.y) * 0.125f;
            qreg[8 * i + 4] = bflo(u.z) * 0.125f; qreg[8 * i + 5] = bfhi(u.z) * 0.125f;
            qreg[8 * i + 6] = bflo(u.w) * 0.125f; qreg[8 * i + 7] = bfhi(u.w) * 0.125f;
        }
    }

    // ---- scores: tap k covers all 16 exo vars at wave-uniform j ----
    const size_t rowbase = kvoff + (size_t)g * NN * DD + (size_t)sub * 16;
    #pragma unroll
    for (int k = 0; k < K; ++k) {
        int j = n + (k - (K >> 1)) * dil;
        float s = NEG_BIG;
        if (j >= 0 && j < NN) {              // wave-uniform branch (cheap s_cbranch)
            size_t off = rowbase + (size_t)j * DD;
            float a0 = 0.f, a1 = 0.f, a2 = 0.f, a3 = 0.f;
            if constexpr (F32) {
                const float4* kp = (const float4*)((const float*)kptr + off);
                float4 kb[4];
                #pragma unroll
                for (int i = 0; i < 4; ++i) kb[i] = kp[i];
                #pragma unroll
                for (int i = 0; i < 4; ++i) {
                    a0 += qreg[4 * i + 0] * kb[i].x; a1 += qreg[4 * i + 1] * kb[i].y;
                    a2 += qreg[4 * i + 2] * kb[i].z; a3 += qreg[4 * i + 3] * kb[i].w;
                }
            } else {
                const uint4* kp = (const uint4*)((const unsigned short*)kptr + off);
                uint4 kb[2];
                #pragma unroll
                for (int i = 0; i < 2; ++i) kb[i] = kp[i];
                #pragma unroll
                for (int i = 0; i < 2; ++i) {
                    a0 += qreg[8 * i + 0] * bflo(kb[i].x); a1 += qreg[8 * i + 1] * bfhi(kb[i].x);
                    a2 += qreg[8 * i + 2] * bflo(kb[i].y); a3 += qreg[8 * i + 3] * bfhi(kb[i].y);
                    a0 += qreg[8 * i + 4] * bflo(kb[i].z); a1 += qreg[8 * i + 5] * bfhi(kb[i].z);
                    a2 += qreg[8 * i + 6] * bflo(kb[i].w); a3 += qreg[8 * i + 7] * bfhi(kb[i].w);
                }
            }
            s = (a0 + a1) + (a2 + a3);
            s += __shfl_xor(s, 1, 64);       // 4-lane butterfly -> full dot in all 4 lanes
            s += __shfl_xor(s, 2, 64);
        }
        if (sub == 0) lds_w[wave][k * CC + g] = s;
    }
    __syncthreads();

    // ---- softmax over the wave's pairs (self pair j==n always valid) ----
    // pair idx pp = k*CC + c -> c = pp & 15 (CC == 16, 64 % 16 == 0)
    float s0 = (lane < nb) ? lds_w[wave][lane] : NEG_BIG;
    float s1 = NEG_BIG;
    if constexpr (K == 5) { if (lane < nb - 64) s1 = lds_w[wave][lane + 64]; }
    float m = fmaxf(s0, s1);
    #pragma unroll
    for (int mm = 32; mm >= 1; mm >>= 1) m = fmaxf(m, __shfl_xor(m, mm, 64));
    float e0 = (s0 <= NEG_BIG) ? 0.f : expf(s0 - m);
    float e1 = (s1 <= NEG_BIG) ? 0.f : expf(s1 - m);
    float tsum = e0 + e1;
    #pragma unroll
    for (int mm = 32; mm >= 1; mm >>= 1) tsum += __shfl_xor(tsum, mm, 64);
    float inv = 1.0f / tsum;
    float gv  = gate[b * CC + (lane & 15)];  // 2KB array, L2-hot broadcast
    lds_w[wave][lane] = e0 * inv * gv;       // gate folded into weight (0 for pad lanes)
    if constexpr (K == 5) { if (lane < nb - 64) lds_w[wave][lane + 64] = e1 * inv * gv; }
    __syncthreads();

    // ---- output: lane = channel; per tap, batch all 16 exo-var loads then FMA ----
    float acc = 0.f;
    #pragma unroll
    for (int k = 0; k < K; ++k) {
        int j = n + (k - (K >> 1)) * dil;
        if (j < 0 || j >= NN) continue;      // wave-uniform skip
        const float* wrow = lds_w[wave] + k * CC;
        const size_t base = kvoff + (size_t)j * DD + lane;
        float vv[CC];
        if constexpr (F32) {
            const float* vb = (const float*)vptr + base;
            #pragma unroll
            for (int c = 0; c < CC; ++c) vv[c] = vb[(size_t)c * (NN * DD)];
        } else {
            const unsigned short* vb = (const unsigned short*)vptr + base;
            #pragma unroll
            for (int c = 0; c < CC; ++c) vv[c] = bf2f(vb[(size_t)c * (NN * DD)]);
        }
        #pragma unroll
        for (int c = 0; c < CC; ++c) acc += wrow[c] * vv[c];
    }
    if constexpr (F32) ((float*)optr)[qoff + lane] = acc;
    else               ((unsigned short*)optr)[qoff + lane] = f2bf(acc);
}

__global__ __launch_bounds__(256) void attn_kernel(
    const void* __restrict__ qptr, const void* __restrict__ kptr,
    const void* __restrict__ vptr, const float* __restrict__ gate,
    const int* __restrict__ flag, void* __restrict__ optr)
{
    __shared__ float lds_w[4][CC * 5];
    const int tid  = threadIdx.x;
    const int wave = tid >> 6;
    const int lane = tid & 63;

    // XCD-locality swizzle: phys block p -> XCD p%8 (round-robin assumption).
    // virt = ((p&7)<<10)|(p>>3) gives each XCD a contiguous range of (b,h) groups
    // so the ~1MB per-(b,h) key/value working set stays L2-resident.
    const int p    = blockIdx.x;
    const int virt = ((p & 7) << 10) | (p >> 3);
    const int gw0  = virt * 4;              // first wave's (b*H + h)*N + n
    const int n    = (gw0 & (NN - 1)) + wave;   // 4 consecutive n, same (b,h)
    const int h    = (gw0 >> 7) & (HH - 1);     // block-uniform
    const int b    = gw0 >> 10;                 // block-uniform
    const int dil  = (int)((DIL_PACK >> (h * 8)) & 0xFF);  // pure SALU lookup
    const bool k5  = (h & 1) && (h != 7);

    const int f = *flag;                     // block-uniform scalar load
    if (f) {
        if (k5) attn_body<true, 5>(qptr, kptr, vptr, gate, optr, b, h, n, dil, wave, lane, lds_w);
        else    attn_body<true, 3>(qptr, kptr, vptr, gate, optr, b, h, n, dil, wave, lane, lds_w);
    } else {
        if (k5) attn_body<false, 5>(qptr, kptr, vptr, gate, optr, b, h, n, dil, wave, lane, lds_w);
        else    attn_body<false, 3>(qptr, kptr, vptr, gate, optr, b, h, n, dil, wave, lane, lds_w);
    }
}

extern "C" void kernel_launch(void* const* d_in, const int* in_sizes, int n_in,
                              void* d_out, int out_size, void* d_ws, size_t ws_size,
                              hipStream_t stream) {
    const void* queries = d_in[0];
    const void* keys    = d_in[1];
    const void* values  = d_in[2];
    const void* w1      = d_in[3];
    const void* b1      = d_in[4];
    const void* w2      = d_in[5];
    const void* b2      = d_in[6];
    // d_in[7] = na_mask: unused — neighborhood structure is regenerated analytically

    int*   flag    = (int*)d_ws;                    // 1 int
    float* gate_ws = (float*)d_ws + 64;             // B*C floats, offset 256 B

    hipLaunchKernelGGL(detect_dtype, dim3(1), dim3(64), 0, stream,
                       (const unsigned short*)queries, flag);
    hipLaunchKernelGGL(gate_kernel, dim3(BB * CC), dim3(1024), 0, stream,
                       values, w1, b1, w2, b2, flag, gate_ws);
    hipLaunchKernelGGL(attn_kernel, dim3(BB * HH * NN / 4), dim3(256), 0, stream,
                       queries, keys, values, gate_ws, flag, d_out);
}